// Round 10
// baseline (1598.578 us; speedup 1.0000x reference)
//
#include <hip/hip_runtime.h>
#include <cstdint>

// PQDenseLayer: out[b,d] = sum_m ( x[b, m*128:+128] @ W[m] + bias[m] )[ idx[m,d] ]
//   K0: split W -> bf16 (Wh,Wl) transposed images [m][cs][k][c], swizzle baked in
//   K1: split-bf16 MFMA GEMM -> proj[m][k][b] f32 (xh*Wh + xh*Wl + xl*Wh);
//       x converted once per block into xh/xl LDS (not per-wave-redundant).
//       A and B use the SAME k-slot mapping (c = lg*8+j) -> correct for any
//       internal HW k-permutation (C/D layout is m89-HW-verified).
//   K2: LDS gather-sum, 3-buffer-deep stage pipeline, manual 2x unroll so no
//       register-rotation movs defeat the counted vmcnt (never 0 mid-loop)

#define M_CB    32
#define CHUNK_C 128
#define KS_K    256
#define DIN     4096

typedef __attribute__((ext_vector_type(8))) short  bf16x8;
typedef __attribute__((ext_vector_type(4))) float  f32x4;

#define GLOAD_LDS16(gp, lp)                                                      \
  __builtin_amdgcn_global_load_lds(                                              \
      (const __attribute__((address_space(1))) void*)(gp),                       \
      (__attribute__((address_space(3))) void*)(lp), 16, 0, 0)

__device__ __forceinline__ ushort f2bf_rne(float f, float* back) {
  unsigned u = __float_as_uint(f);
  unsigned r = (u + 0x7FFFu + ((u >> 16) & 1u)) >> 16;
  *back = __uint_as_float(r << 16);
  return (ushort)r;
}

// ---------------------------------------------------------------------------
// K0: W[m][c][k] f32 -> Wh/Wl images [m][cs] of 16KB: 16B chunk (k,ch) at byte
// (k*64+ch*16)^((k&7)<<4) holds W[c=cs*32+ch*8+j][k] j=0..7 (hi/lo bf16 split).
// Mapping bijective (addr bits 4-6 ^= bits 6-8: invertible). K1 reads with the
// same formula -> consistent.
// ---------------------------------------------------------------------------
__global__ void k0_prep(const float* __restrict__ W, ushort* __restrict__ Whp,
                        ushort* __restrict__ Wlp) {
  const int tid = blockIdx.x * 256 + threadIdx.x;   // 131072 threads
  const int ch = tid & 3;
  const int k  = (tid >> 2) & 255;
  const int cs = (tid >> 10) & 3;
  const int m  = tid >> 12;
  const float* src = W + ((size_t)m * CHUNK_C + cs * 32 + ch * 8) * KS_K + k;
  union { int4 i4; ushort us[8]; } uh, ul;
#pragma unroll
  for (int j = 0; j < 8; ++j) {
    float f = src[(size_t)j * KS_K];
    float back, d2;
    uh.us[j] = f2bf_rne(f, &back);
    ul.us[j] = f2bf_rne(f - back, &d2);
  }
  const size_t img = ((size_t)m * 4 + cs) * 8192;                // ushorts
  const int off_us = ((k * 64 + ch * 16) ^ ((k & 7) << 4)) >> 1; // ushort idx
  *(int4*)&Whp[img + off_us] = uh.i4;
  *(int4*)&Wlp[img + off_us] = ul.i4;
}

// ---------------------------------------------------------------------------
// K1: grid (Bc/64, 32), 256 thr (4 waves). Wave wv owns k in [wv*64, +64).
// 16x16x32 bf16 MFMA; A = W^T tile (rows=k), B = x (cols=b); both use k-slot
// mapping c = lg*8+j (consistent -> layout-independent correctness).
// C/D: col=lane&15, row=(lane>>4)*4+reg  [m89-verified].
// x: global->regs->split once->xh/xl LDS bf16 (chunk-XOR swizzle both sides).
// LDS: wbuf 32KB + xh 16KB + xl 16KB = 64KB -> 2 blocks/CU.
// ---------------------------------------------------------------------------
__global__ __launch_bounds__(256, 2)
void k1_mfma(const float* __restrict__ x, const ushort* __restrict__ Whp,
             const ushort* __restrict__ Wlp, const float* __restrict__ bias,
             float* __restrict__ proj, int b0_chunk, int Bc) {
  const int t    = threadIdx.x;
  const int lane = t & 63;
  const int wv   = t >> 6;
  const int l15  = lane & 15;
  const int lg   = lane >> 4;
  const int m  = blockIdx.y;
  const int bb = blockIdx.x * 64;
  const int wb = t & ~63;             // wave-uniform LDS chunk base

  __shared__ ushort wbuf[16384];      // 32KB: [0,16K)B Wh img, [16K,32K)B Wl
  __shared__ ushort xh[8192];         // 16KB bf16 hi  [b][c] chunk-swizzled
  __shared__ ushort xl[8192];         // 16KB bf16 lo

  // acc init with bias (col=b dim broadcasts bias across lanes' rows)
  f32x4 acc[4][4];
  {
    const float* bp = bias + m * KS_K + wv * 64 + lg * 4;
#pragma unroll
    for (int kt = 0; kt < 4; ++kt) {
      f32x4 bv = *(const f32x4*)&bp[kt * 16];
#pragma unroll
      for (int bt = 0; bt < 4; ++bt) acc[bt][kt] = bv;
    }
  }

  const ushort* wh_img = Whp + (size_t)m * 4 * 8192;
  const ushort* wlo_img = Wlp + (size_t)m * 4 * 8192;

#define STAGE_W(CS)                                                             \
  {                                                                             \
    const ushort* wh_cs = wh_img + (size_t)(CS) * 8192;                         \
    const ushort* wl_cs = wlo_img + (size_t)(CS) * 8192;                        \
    _Pragma("unroll") for (int i_ = 0; i_ < 8; ++i_) {                          \
      const int C_ = t + 256 * i_;                                              \
      const ushort* s_ = (C_ < 1024) ? (wh_cs + C_ * 8) : (wl_cs + (C_ - 1024) * 8); \
      GLOAD_LDS16(s_, (char*)wbuf + (size_t)(wb + 256 * i_) * 16);              \
    }                                                                           \
  }

  // ---- x -> regs (issued first: oldest in vmcnt queue) ----
  const int bloc = t >> 2, c4 = t & 3;
  const float* xg = x + (size_t)(b0_chunk + bb + bloc) * DIN + m * CHUNK_C + c4 * 32;
  float4 xv[8];
#pragma unroll
  for (int j = 0; j < 8; ++j) xv[j] = *(const float4*)&xg[4 * j];

  STAGE_W(0);   // W cs=0 in flight while we convert

  // ---- split once: 32 f32 -> 4x(8 hi, 8 lo), write swizzled ----
  {
    union { int4 i4; ushort us[8]; } H[4], L[4];
#pragma unroll
    for (int cj = 0; cj < 4; ++cj) {
#pragma unroll
      for (int e = 0; e < 8; ++e) {
        float f = ((const float*)&xv[cj * 2 + (e >> 2)])[e & 3];
        float back, d2;
        H[cj].us[e] = f2bf_rne(f, &back);
        L[cj].us[e] = f2bf_rne(f - back, &d2);
      }
    }
#pragma unroll
    for (int cj = 0; cj < 4; ++cj) {
      const int ch = c4 * 4 + cj;
      const int off = bloc * 256 + ((ch ^ (bloc & 7)) << 4);
      *(int4*)((char*)xh + off) = H[cj].i4;
      *(int4*)((char*)xl + off) = L[cj].i4;
    }
  }
  asm volatile("s_waitcnt vmcnt(0)" ::: "memory");
  __syncthreads();

  for (int cs = 0; cs < 4; ++cs) {
    // A-frags: 8 b128 reads, 8 lanes/bank-group (swizzle-balanced)
    bf16x8 Ah[4], Al[4];
#pragma unroll
    for (int kt = 0; kt < 4; ++kt) {
      const int k = wv * 64 + kt * 16 + l15;
      const int off = (k * 64 + lg * 16) ^ ((k & 7) << 4);
      Ah[kt] = *(const bf16x8*)((const char*)wbuf + off);
      Al[kt] = *(const bf16x8*)((const char*)wbuf + 16384 + off);
    }
#pragma unroll
    for (int bt = 0; bt < 4; ++bt) {
      const int b = bt * 16 + l15;
      const int off = b * 256 + (((cs * 4 + lg) ^ (b & 7)) << 4);
      bf16x8 Bh = *(const bf16x8*)((const char*)xh + off);
      bf16x8 Bl = *(const bf16x8*)((const char*)xl + off);
#pragma unroll
      for (int kt = 0; kt < 4; ++kt) {
        acc[bt][kt] = __builtin_amdgcn_mfma_f32_16x16x32_bf16(Ah[kt], Bh, acc[bt][kt], 0, 0, 0);
        acc[bt][kt] = __builtin_amdgcn_mfma_f32_16x16x32_bf16(Ah[kt], Bl, acc[bt][kt], 0, 0, 0);
        acc[bt][kt] = __builtin_amdgcn_mfma_f32_16x16x32_bf16(Al[kt], Bh, acc[bt][kt], 0, 0, 0);
      }
    }
    if (cs < 3) {
      __syncthreads();                 // all waves done reading wbuf
      STAGE_W(cs + 1);
      asm volatile("s_waitcnt vmcnt(0)" ::: "memory");
      __syncthreads();
    }
  }
#undef STAGE_W

  // store proj[m][k][b]
#pragma unroll
  for (int bt = 0; bt < 4; ++bt)
#pragma unroll
    for (int kt = 0; kt < 4; ++kt)
#pragma unroll
      for (int j = 0; j < 4; ++j) {
        const int row = wv * 64 + kt * 16 + lg * 4 + j;
        proj[(size_t)(m * KS_K + row) * Bc + bb + bt * 16 + l15] = acc[bt][kt][j];
      }
}

// ---------------------------------------------------------------------------
// K2: grid (Bc/32, D_out/2048), 512 thr. Stage pipeline 3 buffers deep via
// counted vmcnt; manual 2x unroll (iva/ivb alternate) -> NO rotation movs ->
// nothing ever forces a wait on the newest loads.
// Issue order per iter m: [idx(m+1)] [STAGE(m+3)] [gather m] [vmcnt(thr)]
// [s_barrier]. Steady state entering iter m: {S(m+1), idx(m), S(m+2)} = 16
// outstanding; gather m's idx auto-wait (vmcnt<=16) drains S(m+1)
// just-in-time; tails 12/8; 2 stages always in flight. Never vmcnt(0).
// ---------------------------------------------------------------------------
__global__ __launch_bounds__(512, 2)
void k2_gather(const float* __restrict__ proj, const int* __restrict__ idx,
               float* __restrict__ out, int b0_chunk, int Bc, int D_out) {
  const int t  = threadIdx.x;
  const int q  = t & 7;
  const int g  = t >> 3;
  const int b0 = blockIdx.x * 32;
  const int dbase = blockIdx.y * 2048 + g * 32;

  __shared__ float pb[4][8192];   // 4 x 32KB = 128 KB

  f32x4 acc[32];
#pragma unroll
  for (int j = 0; j < 32; ++j) acc[j] = (f32x4){0.f, 0.f, 0.f, 0.f};

  const int q16 = q << 4;
  const int* ixp = idx + dbase;
  const int wbk = t & ~63;

#define STAGE(MM, BUF)                                                          \
  {                                                                             \
    const float* src_ = proj + (size_t)(MM) * KS_K * Bc + b0;                   \
    _Pragma("unroll") for (int i_ = 0; i_ < 4; ++i_) {                          \
      const int C_ = t + 512 * i_;                                              \
      const int k_ = C_ >> 3, qp_ = C_ & 7;                                     \
      GLOAD_LDS16(src_ + (size_t)k_ * Bc + 4 * qp_,                             \
                  (char*)(BUF) + (size_t)(wbk + 512 * i_) * 16);                \
    }                                                                           \
  }
#define LOADIDX(MM, DST)                                                        \
  {                                                                             \
    const int* ix_ = ixp + (size_t)(MM) * D_out;                                \
    _Pragma("unroll") for (int a_ = 0; a_ < 8; ++a_)                            \
      (DST)[a_] = *(const int4*)&ix_[4 * a_];                                   \
  }
#define GATHER(IVU)                                                             \
  {                                                                             \
    _Pragma("unroll") for (int a_ = 0; a_ < 8; ++a_) {                          \
      const f32x4 v0_ = *(const f32x4*)(pbase + ((IVU)[a_].x << 7));            \
      const f32x4 v1_ = *(const f32x4*)(pbase + ((IVU)[a_].y << 7));            \
      const f32x4 v2_ = *(const f32x4*)(pbase + ((IVU)[a_].z << 7));            \
      const f32x4 v3_ = *(const f32x4*)(pbase + ((IVU)[a_].w << 7));            \
      acc[4 * a_ + 0] += v0_; acc[4 * a_ + 1] += v1_;                           \
      acc[4 * a_ + 2] += v2_; acc[4 * a_ + 3] += v3_;                           \
    }                                                                           \
  }
#define K2ITER(MM, IVU, IVL)                                                    \
  {                                                                             \
    if ((MM) + 1 < M_CB) LOADIDX((MM) + 1, IVL);                                \
    __builtin_amdgcn_sched_barrier(0);                                          \
    if ((MM) + 3 < M_CB) STAGE((MM) + 3, pb[((MM) + 3) & 3]);                   \
    __builtin_amdgcn_sched_barrier(0);                                          \
    const char* pbase = (const char*)&pb[(MM) & 3][0] + q16;                    \
    GATHER(IVU);                                                                \
    if ((MM) < M_CB - 1) {                                                      \
      if ((MM) <= M_CB - 4)      { asm volatile("s_waitcnt vmcnt(16)" ::: "memory"); } \
      else if ((MM) == M_CB - 3) { asm volatile("s_waitcnt vmcnt(12)" ::: "memory"); } \
      else                       { asm volatile("s_waitcnt vmcnt(8)"  ::: "memory"); } \
      __builtin_amdgcn_s_barrier();                                             \
      __builtin_amdgcn_sched_barrier(0);                                        \
    }                                                                           \
  }

  int4 iva[8], ivb[8];
  // prologue: S0, idx0, S1, S2 -> 20 outstanding; force S0: vmcnt(16)
  STAGE(0, pb[0]);
  __builtin_amdgcn_sched_barrier(0);
  LOADIDX(0, iva);
  __builtin_amdgcn_sched_barrier(0);
  STAGE(1, pb[1]);
  STAGE(2, pb[2]);
  asm volatile("s_waitcnt vmcnt(16)" ::: "memory");
  __builtin_amdgcn_s_barrier();
  __builtin_amdgcn_sched_barrier(0);

  for (int mm = 0; mm < M_CB; mm += 2) {
    K2ITER(mm, iva, ivb);
    K2ITER(mm + 1, ivb, iva);
  }
#undef K2ITER
#undef GATHER
#undef LOADIDX
#undef STAGE

  // epilogue: register transpose -> d-major dwordx4 stores; across a=0..7 each
  // (b-row, g) assembles one full 128B line
  float* op = out + (size_t)(b0_chunk + b0 + 4 * q) * D_out + dbase;
#pragma unroll
  for (int a = 0; a < 8; ++a) {
    f32x4 o0, o1, o2, o3;
    o0[0]=acc[4*a+0][0]; o0[1]=acc[4*a+1][0]; o0[2]=acc[4*a+2][0]; o0[3]=acc[4*a+3][0];
    o1[0]=acc[4*a+0][1]; o1[1]=acc[4*a+1][1]; o1[2]=acc[4*a+2][1]; o1[3]=acc[4*a+3][1];
    o2[0]=acc[4*a+0][2]; o2[1]=acc[4*a+1][2]; o2[2]=acc[4*a+2][2]; o2[3]=acc[4*a+3][2];
    o3[0]=acc[4*a+0][3]; o3[1]=acc[4*a+1][3]; o3[2]=acc[4*a+2][3]; o3[3]=acc[4*a+3][3];
    *(f32x4*)(op + 0 * (size_t)D_out + 4 * a) = o0;
    *(f32x4*)(op + 1 * (size_t)D_out + 4 * a) = o1;
    *(f32x4*)(op + 2 * (size_t)D_out + 4 * a) = o2;
    *(f32x4*)(op + 3 * (size_t)D_out + 4 * a) = o3;
  }
}

// ---------------------------------------------------------------------------
extern "C" void kernel_launch(void* const* d_in, const int* in_sizes, int n_in,
                              void* d_out, int out_size, void* d_ws, size_t ws_size,
                              hipStream_t stream) {
  const float* x    = (const float*)d_in[0];
  const float* W    = (const float*)d_in[1];
  const float* bias = (const float*)d_in[2];
  const int*   idx  = (const int*)d_in[3];
  float* out = (float*)d_out;

  ushort* Whp = (ushort*)d_ws;                              // 2 MB
  ushort* Wlp = (ushort*)((char*)d_ws + (2u << 20));        // 2 MB
  float*  proj = (float*)((char*)d_ws + (4u << 20));

  const int B     = in_sizes[0] / DIN;     // 8192
  const int D_out = in_sizes[3] / M_CB;    // 4096

  size_t maxBc = (ws_size - (4u << 20)) / ((size_t)M_CB * KS_K * sizeof(float));
  int Bc = 4096;
  if ((size_t)Bc > maxBc) Bc = (int)(maxBc & ~(size_t)63);
  if (Bc > B) Bc = B;
  if (Bc < 64) Bc = 64;

  k0_prep<<<512, 256, 0, stream>>>(W, Whp, Wlp);

  for (int b0 = 0; b0 < B; b0 += Bc) {
    int cb = (B - b0 < Bc) ? (B - b0) : Bc;
    dim3 g1(cb / 64, M_CB);
    k1_mfma<<<g1, 256, 0, stream>>>(x, Whp, Wlp, bias, proj, b0, cb);
    dim3 g2(cb / 32, D_out / 2048);
    k2_gather<<<g2, 512, 0, stream>>>(proj, idx, out, b0, cb, D_out);
  }
}